// Round 12
// baseline (150.910 us; speedup 1.0000x reference)
//
#include <hip/hip_runtime.h>
#include <math.h>

// Problem constants: B=4, S=4096, H=1024, M=256, chunk=64
#define BB 4
#define SS 4096
#define HH 1024
#define MM 256
#define CHUNK 64
#define NCHUNK 64
#define ROWS (BB*SS)          // 16384
#define QKV_LD 768
#define DECAY_F 0.99

typedef unsigned short u16;
typedef __attribute__((ext_vector_type(8))) short bf16x8;
typedef __attribute__((ext_vector_type(8))) unsigned short u16x8;
typedef __attribute__((ext_vector_type(4))) float f32x4;

__device__ inline u16 f2b(float f) {
  union { float f; unsigned u; } v; v.f = f;
  unsigned r = v.u + 0x7FFF + ((v.u >> 16) & 1);   // RNE
  return (u16)(r >> 16);
}
__device__ inline float b2f(u16 h) {
  union { unsigned u; float f; } v; v.u = ((unsigned)h) << 16; return v.f;
}

// async global->LDS, 16B per lane. LDS dest wave-uniform base; global src per-lane.
__device__ inline void gload16(const void* g, void* l) {
  __builtin_amdgcn_global_load_lds(
      (const __attribute__((address_space(1))) unsigned int*)g,
      (__attribute__((address_space(3))) unsigned int*)l, 16, 0, 0);
}

// all 4 weight casts in one launch
__global__ __launch_bounds__(256) void cast_w_kernel(const float* __restrict__ Wq,
                                                     const float* __restrict__ Wk,
                                                     const float* __restrict__ Wv,
                                                     const float* __restrict__ Wo,
                                                     u16* __restrict__ Wqkv_b,
                                                     u16* __restrict__ Wo_b) {
  int b = blockIdx.x, which = b >> 8;
  int i = ((b & 255) << 8) + threadIdx.x;
  const float* src = which == 0 ? Wq : which == 1 ? Wk : which == 2 ? Wv : Wo;
  u16* dst = which < 3 ? Wqkv_b + which * (MM * HH) : Wo_b;
  float4 v = reinterpret_cast<const float4*>(src)[i];
  ushort4 o;
  o.x = f2b(v.x); o.y = f2b(v.y); o.z = f2b(v.z); o.w = f2b(v.w);
  reinterpret_cast<ushort4*>(dst)[i] = o;
}

// ---------------------------------------------------------------------------
// 256x256 8-phase MFMA GEMM (C = A * B^T), 512 thr = 8 waves (2M x 4N),
// wave tile 128x64, BK=64, fragment-major conflict-free LDS, counted vmcnt,
// setprio MFMA clusters. Round-7 schedule.
// A_F32 = 1: A is fp32 read straight from global (x) -- reg-staged with the
// loads issued at phase 0 (OLDER in the VMEM queue than B's gload_lds, so the
// compiler's auto-wait before the phase-3 ds_write is vmcnt(4), leaving B
// prefetches in flight). Kills the separate cast_x kernel.
// ---------------------------------------------------------------------------
template<int A_F32, int OUT_BF16>
__global__ __launch_bounds__(512, 2) void gemm256(const void* __restrict__ Ap,
                                                  const u16* __restrict__ B,
                                                  void* __restrict__ Cv,
                                                  int K, int lda, int ldb, int ldc) {
  __shared__ bf16x8 LA[2][2][16][64];   // 64 KB
  __shared__ bf16x8 LB[2][2][16][64];   // 64 KB
  const int tid = threadIdx.x, lane = tid & 63, wv = tid >> 6;
  const int wr = wv >> 2, wc = wv & 3;  // 2 x 4 wave grid

  // XCD-chunked bijective swizzle (nwg = 192 or 256, both % 8 == 0)
  const int gx = gridDim.x;
  const int nwg = gx * gridDim.y;
  const int lin = blockIdx.y * gx + blockIdx.x;
  const int chunk = nwg >> 3;
  const int orig = (lin & 7) * chunk + (lin >> 3);
  const int bx = orig % gx, by = orig / gx;
  const int row0 = by * 256, col0 = bx * 256;
  const int NT = K >> 6;

  const int fr = lane & 15;            // row within a 16-row tile
  const int kg = (lane >> 4) << 3;     // k-offset (elements) within 32-wide ksub

  // ---- A fp32 register staging (A_F32 path) ----
  float4 rA[2][2][2];                  // [tile j][ksub s][half] -- static idx only
  auto loadA = [&](int kt) {
    if constexpr (A_F32) {
#pragma unroll
      for (int j = 0; j < 2; ++j)
#pragma unroll
        for (int s = 0; s < 2; ++s) {
          const float* g = (const float*)Ap +
              (size_t)(row0 + (wv + j * 8) * 16 + fr) * (size_t)lda + kt * 64 + s * 32 + kg;
          rA[j][s][0] = *(const float4*)g;
          rA[j][s][1] = *(const float4*)(g + 4);
        }
    }
  };
  auto writeA = [&](int db_) {
    if constexpr (A_F32) {
#pragma unroll
      for (int j = 0; j < 2; ++j)
#pragma unroll
        for (int s = 0; s < 2; ++s) {
          float4 p = rA[j][s][0], q = rA[j][s][1];
          unsigned w0, w1, w2, w3;
          asm("v_cvt_pk_bf16_f32 %0, %1, %2" : "=v"(w0) : "v"(p.x), "v"(p.y));
          asm("v_cvt_pk_bf16_f32 %0, %1, %2" : "=v"(w1) : "v"(p.z), "v"(p.w));
          asm("v_cvt_pk_bf16_f32 %0, %1, %2" : "=v"(w2) : "v"(q.x), "v"(q.y));
          asm("v_cvt_pk_bf16_f32 %0, %1, %2" : "=v"(w3) : "v"(q.z), "v"(q.w));
          uint4 wd; wd.x = w0; wd.y = w1; wd.z = w2; wd.w = w3;
          *reinterpret_cast<uint4*>(&LA[db_][s][wv + j * 8][lane]) = wd;
        }
    }
  };
  auto stageA = [&](int kt, int db_, int tile) {     // A_F32 == 0 path
    const u16* g = (const u16*)Ap + (size_t)(row0 + tile * 16 + fr) * (size_t)lda + kt * 64 + kg;
    gload16(g,      &LA[db_][0][tile][0]);
    gload16(g + 32, &LA[db_][1][tile][0]);
  };
  auto stageB = [&](int kt, int db_, int tile) {
    const u16* g = B + (size_t)(col0 + tile * 16 + fr) * (size_t)ldb + kt * 64 + kg;
    gload16(g,      &LB[db_][0][tile][0]);
    gload16(g + 32, &LB[db_][1][tile][0]);
  };

  bf16x8 aq[4][2], bq[4][2];
  auto readAquad = [&](int db_, int h) {
#pragma unroll
    for (int i = 0; i < 4; ++i)
#pragma unroll
      for (int s = 0; s < 2; ++s)
        aq[i][s] = LA[db_][s][wr * 8 + h * 4 + i][lane];
  };
  auto readB2 = [&](int db_, int nh) {
#pragma unroll
    for (int j = 0; j < 2; ++j)
#pragma unroll
      for (int s = 0; s < 2; ++s)
        bq[nh * 2 + j][s] = LB[db_][s][wc * 4 + nh * 2 + j][lane];
  };

  f32x4 acc[8][4] = {};
  auto cluster = [&](int h, int nh) {
#pragma unroll
    for (int i = 0; i < 4; ++i)
#pragma unroll
      for (int j = 0; j < 2; ++j)
#pragma unroll
        for (int s = 0; s < 2; ++s)
          acc[h * 4 + i][nh * 2 + j] = __builtin_amdgcn_mfma_f32_16x16x32_bf16(
              aq[i][s], bq[nh * 2 + j][s], acc[h * 4 + i][nh * 2 + j], 0, 0, 0);
  };

  // ---- prologue: stage K-tile 0 into dbuf 0 ----
  if constexpr (A_F32) {
    loadA(0);                               // oldest in VMEM queue
    stageB(0, 0, wv); stageB(0, 0, wv + 8); // 4 gload_lds, newer
    writeA(0);                              // compiler auto-waits A only (vmcnt(4))
  } else {
    stageA(0, 0, wv); stageA(0, 0, wv + 8);
    stageB(0, 0, wv); stageB(0, 0, wv + 8);
  }

  for (int kt = 0; kt < NT; ++kt) {
    const int db = kt & 1, sb = db ^ 1;
    const bool pf = (kt + 1 < NT);
    // ---- phase 0 ----
    if (pf) { if constexpr (A_F32) loadA(kt + 1); else stageA(kt + 1, sb, wv); }
    if (pf) {
      if constexpr (A_F32) asm volatile("s_waitcnt vmcnt(8)" ::: "memory");
      else                 asm volatile("s_waitcnt vmcnt(2)" ::: "memory");
    } else   asm volatile("s_waitcnt vmcnt(0)" ::: "memory");
    if constexpr (A_F32) asm volatile("s_waitcnt lgkmcnt(0)" ::: "memory"); // p3 ds_writes flushed
    __builtin_amdgcn_s_barrier();
    asm volatile("" ::: "memory");
    readAquad(db, 0);
    readB2(db, 0);
    __builtin_amdgcn_s_setprio(1); cluster(0, 0); __builtin_amdgcn_s_setprio(0);
    __builtin_amdgcn_s_barrier();
    // ---- phase 1 ----
    readB2(db, 1);
    if (pf) { if constexpr (A_F32) stageB(kt + 1, sb, wv); else stageA(kt + 1, sb, wv + 8); }
    __builtin_amdgcn_s_barrier();
    __builtin_amdgcn_s_setprio(1); cluster(0, 1); __builtin_amdgcn_s_setprio(0);
    __builtin_amdgcn_s_barrier();
    // ---- phase 2 ----
    readAquad(db, 1);
    if (pf) { if constexpr (A_F32) stageB(kt + 1, sb, wv + 8); else stageB(kt + 1, sb, wv); }
    __builtin_amdgcn_s_barrier();
    __builtin_amdgcn_s_setprio(1); cluster(1, 0); __builtin_amdgcn_s_setprio(0);
    __builtin_amdgcn_s_barrier();
    // ---- phase 3 ----
    if (pf) { if constexpr (A_F32) writeA(sb); else stageB(kt + 1, sb, wv + 8); }
    __builtin_amdgcn_s_barrier();
    __builtin_amdgcn_s_setprio(1); cluster(1, 1); __builtin_amdgcn_s_setprio(0);
    __builtin_amdgcn_s_barrier();
  }

  // C/D layout: col = lane&15, row = (lane>>4)*4 + reg
  const int r4 = (lane >> 4) << 2;
  const int cc = lane & 15;
#pragma unroll
  for (int mi = 0; mi < 8; ++mi)
#pragma unroll
    for (int nj = 0; nj < 4; ++nj)
#pragma unroll
      for (int r = 0; r < 4; ++r) {
        int lr = wr * 128 + mi * 16 + r4 + r;
        int lc = wc * 64 + nj * 16 + cc;
        float vv = acc[mi][nj][r];
        if (OUT_BF16) ((u16*)Cv)[(size_t)(row0 + lr) * ldc + col0 + lc] = f2b(vv);
        else          ((float*)Cv)[(size_t)(row0 + lr) * ldc + col0 + lc] = vv;
      }
}

// ---------------------------------------------------------------------------
// 128x128 MFMA GEMM (proven), depth-3 gload_lds pipeline, counted vmcnt.
// ---------------------------------------------------------------------------
#define M_OUTER 2   // A=vT,B=kT (ld 16384), K=256 per chunk t, C=outer[t]*scale
#define M_RETR  3   // A=q (qkv ld 768, chunk rows), B=Mprev_b[t] bf16 (ld 256)

template<int MODE>
__global__ __launch_bounds__(256) void gemm128(const u16* __restrict__ A,
                                               const u16* __restrict__ Bg,
                                               void* __restrict__ Cv,
                                               int K, int lda, int ldb,
                                               float scale) {
  __shared__ bf16x8 As[3][512];
  __shared__ bf16x8 Bs[3][512];
  const int tid = threadIdx.x, lane = tid & 63, wv = tid >> 6;
  const int wr = wv >> 1, wc = wv & 1;
  const int t = blockIdx.z;
  const int bx = blockIdx.x, by = blockIdx.y;
  const int row0 = by * 128;
  const int col0 = bx * 128;
  const int NK = K >> 5;
  const u16* Bbase = (MODE == M_RETR) ? (Bg + (size_t)t * (MM * MM)) : Bg;

  auto stage = [&](int ks, int buf) {
    int koff;
    if (MODE == M_OUTER) koff = ((ks >> 1) << 12) + t * CHUNK + ((ks & 1) << 5);
    else                 koff = ks << 5;
#pragma unroll
    for (int j = 0; j < 2; ++j) {
      int m = j * 4 + wv;
      int rf = m * 16 + (lane & 15);
      size_t arow;
      if (MODE == M_RETR)
        arow = (size_t)(2 * by + (rf >> 6)) * SS + (size_t)t * CHUNK + (rf & 63);
      else
        arow = (size_t)(row0 + rf);
      const u16* ga = A + arow * (size_t)lda + koff + ((lane >> 4) << 3);
      gload16(ga, &As[buf][m * 64]);
      const u16* gb = Bbase + (size_t)(col0 + rf) * ldb + koff + ((lane >> 4) << 3);
      gload16(gb, &Bs[buf][m * 64]);
    }
  };

  f32x4 acc[4][4] = {};
  stage(0, 0);
  stage(1, 1);
  int rb = 0, sb = 2;
  for (int ks = 0; ks < NK; ++ks) {
    if (ks + 1 < NK) asm volatile("s_waitcnt vmcnt(4)" ::: "memory");
    else             asm volatile("s_waitcnt vmcnt(0)" ::: "memory");
    __builtin_amdgcn_s_barrier();
    asm volatile("" ::: "memory");
    if (ks + 2 < NK) stage(ks + 2, sb);
    bf16x8 af[4], bfr[4];
#pragma unroll
    for (int m = 0; m < 4; ++m) af[m] = As[rb][(wr * 4 + m) * 64 + lane];
#pragma unroll
    for (int n = 0; n < 4; ++n) bfr[n] = Bs[rb][(wc * 4 + n) * 64 + lane];
#pragma unroll
    for (int m = 0; m < 4; ++m)
#pragma unroll
      for (int n = 0; n < 4; ++n)
        acc[m][n] = __builtin_amdgcn_mfma_f32_16x16x32_bf16(af[m], bfr[n], acc[m][n], 0, 0, 0);
    rb = (rb == 2) ? 0 : rb + 1;
    sb = (sb == 2) ? 0 : sb + 1;
  }

  const int r4 = (lane >> 4) << 2;
  const int cc = lane & 15;
#pragma unroll
  for (int m = 0; m < 4; ++m)
#pragma unroll
    for (int n = 0; n < 4; ++n)
#pragma unroll
      for (int r = 0; r < 4; ++r) {
        int lr = wr * 64 + m * 16 + r4 + r;
        int lc = wc * 64 + n * 16 + cc;
        float vv = acc[m][n][r];
        if (MODE == M_OUTER) {
          ((float*)Cv)[(size_t)t * (MM * MM) + (size_t)(row0 + lr) * MM + col0 + lc] = vv * scale;
        } else {  // M_RETR
          size_t rowg = (size_t)(2 * by + (lr >> 6)) * SS + (size_t)t * CHUNK + (lr & 63);
          ((u16*)Cv)[rowg * MM + col0 + lc] = f2b(vv);
        }
      }
}

// ---------------------------------------------------------------------------
// Fused l2norm + transpose: qkv cols [256,512)=k, [512,768)=v -> kT,vT
// ---------------------------------------------------------------------------
__global__ __launch_bounds__(256) void l2normT_kernel(const u16* __restrict__ qkv,
                                                      u16* __restrict__ kT,
                                                      u16* __restrict__ vT) {
  __shared__ u16 T[256][72];
  __shared__ float ps[64][4];
  __shared__ float inv[64];
  const int tid = threadIdx.x;
  const int q = tid >> 6, rl = tid & 63;
  const int row0 = blockIdx.x * 64;
#pragma unroll 1
  for (int seg = 0; seg < 2; ++seg) {
    u16* dstT = seg ? vT : kT;
    const int segbase = 256 + seg * 256;
    float ss = 0.f;
#pragma unroll
    for (int i = 0; i < 8; ++i) {
      u16x8 v = *reinterpret_cast<const u16x8*>(
          qkv + (size_t)(row0 + rl) * QKV_LD + segbase + q * 64 + i * 8);
#pragma unroll
      for (int e = 0; e < 8; ++e) {
        float f = b2f(v[e]);
        ss += f * f;
        T[q * 64 + i * 8 + e][rl] = v[e];
      }
    }
    ps[rl][q] = ss;
    __syncthreads();
    if (tid < 64) {
      float s = ps[tid][0] + ps[tid][1] + ps[tid][2] + ps[tid][3];
      inv[tid] = 1.0f / fmaxf(sqrtf(s), 1e-12f);
    }
    __syncthreads();
#pragma unroll
    for (int p = 0; p < 8; ++p) {
      int c = p * 32 + q * 8 + (rl >> 3);
      int r0 = (rl & 7) * 8;
      u16x8 val = *reinterpret_cast<const u16x8*>(&T[c][r0]);
      u16x8 o;
#pragma unroll
      for (int e = 0; e < 8; ++e) o[e] = f2b(b2f(val[e]) * inv[r0 + e]);
      *reinterpret_cast<u16x8*>(dstT + (size_t)c * ROWS + row0 + r0) = o;
    }
    __syncthreads();
  }
}

// ---------------------------------------------------------------------------
// Decay prefix over t: Mprev_b[t] = bf16(run); run = decay*run + outer[t].
// ---------------------------------------------------------------------------
__global__ __launch_bounds__(256) void prefix_kernel(const float* __restrict__ outer,
                                                     const float* __restrict__ M0,
                                                     u16* __restrict__ Mprev_b,
                                                     float decay_c) {
  int ij = blockIdx.x * 256 + threadIdx.x;
  float run = M0[ij];
  float pre[8];
#pragma unroll
  for (int d = 0; d < 8; ++d) pre[d] = outer[(size_t)d * (MM * MM) + ij];
#pragma unroll 1
  for (int tb = 0; tb < NCHUNK; tb += 8) {
#pragma unroll
    for (int d = 0; d < 8; ++d) {
      int tc = tb + d;
      float o = pre[d];
      if (tb + 8 < NCHUNK) pre[d] = outer[(size_t)(tc + 8) * (MM * MM) + ij];
      Mprev_b[(size_t)tc * (MM * MM) + ij] = f2b(run);
      run = decay_c * run + o;
    }
  }
}

// ---------------------------------------------------------------------------
extern "C" void kernel_launch(void* const* d_in, const int* in_sizes, int n_in,
                              void* d_out, int out_size, void* d_ws, size_t ws_size,
                              hipStream_t stream) {
  const float* x  = (const float*)d_in[0];
  const float* Wq = (const float*)d_in[1];
  const float* Wk = (const float*)d_in[2];
  const float* Wv = (const float*)d_in[3];
  const float* Wo = (const float*)d_in[4];
  const float* M0 = (const float*)d_in[5];
  float* out = (float*)d_out;

  char* ws = (char*)d_ws;
  u16*   qkv_b   = (u16*)(ws + 33554432);    // 16384x768 bf16 (24M)
  u16*   Wqkv_b  = (u16*)(ws + 58720256);    // 768x1024 bf16 (1.5M)
  u16*   Wo_b    = (u16*)(ws + 60293120);    // 1024x256 bf16 (0.5M)
  u16*   kT      = (u16*)(ws);               // 8M
  u16*   vT      = (u16*)(ws + 8388608);     // 8M
  float* outer   = (float*)(ws + 16777216);  // 64x256x256 fp32 (16M)
  u16*   Mprev_b = (u16*)(ws);               // 8M, over dead kT
  u16*   r_b     = (u16*)(ws + 8388608);     // 8M, over dead vT

  const float scale   = 1.0f / (BB * CHUNK);
  const float decay_c = (float)pow(DECAY_F, (double)CHUNK);
  dim3 blk(256), blk512(512);

  // 1) weight casts (x is consumed fp32 directly by the fused QKV GEMM)
  cast_w_kernel<<<1024, blk, 0, stream>>>(Wq, Wk, Wv, Wo, Wqkv_b, Wo_b);
  // 2) fused cast + QKV projection: (16384x1024 f32)x(768x1024 bf16)^T -> qkv_b
  gemm256<1, 1><<<dim3(QKV_LD / 256, ROWS / 256), blk512, 0, stream>>>(
      x, Wqkv_b, qkv_b, HH, HH, HH, QKV_LD);
  // 3) l2norm k,v + transpose -> kT, vT
  l2normT_kernel<<<ROWS / 64, blk, 0, stream>>>(qkv_b, kT, vT);
  // 4) per-chunk outer products: outer[t] = scale * vT_t * kT_t^T
  gemm128<M_OUTER><<<dim3(2, 2, NCHUNK), blk, 0, stream>>>(
      vT, kT, outer, MM, ROWS, ROWS, scale);
  // 5) decay prefix scan -> Mprev_b (bf16)
  prefix_kernel<<<(MM * MM) / 256, blk, 0, stream>>>(outer, M0, Mprev_b, decay_c);
  // 6) retrieval: r = q @ Mprev_b[t]^T -> r_b (bf16)
  gemm128<M_RETR><<<dim3(2, 2, NCHUNK), blk, 0, stream>>>(
      qkv_b, Mprev_b, r_b, MM, QKV_LD, MM, 0.f);
  // 7) output projection: (16384x256)x(1024x256)^T -> fp32 out
  gemm256<0, 0><<<dim3(HH / 256, ROWS / 256), blk512, 0, stream>>>(
      r_b, Wo_b, out, MM, MM, MM, HH);
}

// Round 13
// 140.235 us; speedup vs baseline: 1.0761x; 1.0761x over previous
//
#include <hip/hip_runtime.h>
#include <math.h>

// Problem constants: B=4, S=4096, H=1024, M=256, chunk=64
#define BB 4
#define SS 4096
#define HH 1024
#define MM 256
#define CHUNK 64
#define NCHUNK 64
#define ROWS (BB*SS)          // 16384
#define QKV_LD 768
#define DECAY_F 0.99

typedef unsigned short u16;
typedef __attribute__((ext_vector_type(8))) short bf16x8;
typedef __attribute__((ext_vector_type(8))) unsigned short u16x8;
typedef __attribute__((ext_vector_type(4))) float f32x4;

__device__ inline u16 f2b(float f) {
  union { float f; unsigned u; } v; v.f = f;
  unsigned r = v.u + 0x7FFF + ((v.u >> 16) & 1);   // RNE
  return (u16)(r >> 16);
}
__device__ inline float b2f(u16 h) {
  union { unsigned u; float f; } v; v.u = ((unsigned)h) << 16; return v.f;
}

// async global->LDS, 16B per lane. LDS dest wave-uniform base; global src per-lane.
__device__ inline void gload16(const void* g, void* l) {
  __builtin_amdgcn_global_load_lds(
      (const __attribute__((address_space(1))) unsigned int*)g,
      (__attribute__((address_space(3))) unsigned int*)l, 16, 0, 0);
}

// ---------------------------------------------------------------------------
// fp32 -> bf16 cast of x
// ---------------------------------------------------------------------------
__global__ __launch_bounds__(256) void cast_x_kernel(const float* __restrict__ src,
                                                     u16* __restrict__ dst) {
  int i = blockIdx.x * 256 + threadIdx.x;
  float4 v = reinterpret_cast<const float4*>(src)[i];
  ushort4 o;
  o.x = f2b(v.x); o.y = f2b(v.y); o.z = f2b(v.z); o.w = f2b(v.w);
  reinterpret_cast<ushort4*>(dst)[i] = o;
}

// all 4 weight casts in one launch
__global__ __launch_bounds__(256) void cast_w_kernel(const float* __restrict__ Wq,
                                                     const float* __restrict__ Wk,
                                                     const float* __restrict__ Wv,
                                                     const float* __restrict__ Wo,
                                                     u16* __restrict__ Wqkv_b,
                                                     u16* __restrict__ Wo_b) {
  int b = blockIdx.x, which = b >> 8;
  int i = ((b & 255) << 8) + threadIdx.x;
  const float* src = which == 0 ? Wq : which == 1 ? Wk : which == 2 ? Wv : Wo;
  u16* dst = which < 3 ? Wqkv_b + which * (MM * HH) : Wo_b;
  float4 v = reinterpret_cast<const float4*>(src)[i];
  ushort4 o;
  o.x = f2b(v.x); o.y = f2b(v.y); o.z = f2b(v.z); o.w = f2b(v.w);
  reinterpret_cast<ushort4*>(dst)[i] = o;
}

// ---------------------------------------------------------------------------
// 256x256 8-phase MFMA GEMM (C = A * B^T), 512 thr = 8 waves (2M x 4N),
// wave tile 128x64, BK=64 (2 ksub of 32), fragment-major conflict-free LDS,
// gload_lds staging, counted vmcnt(2) once per K-tile, setprio MFMA clusters.
// Per K-tile: 4 phases x {ds_read subtile | 2 gload_lds (kt+1 -> dead dbuf)
//   -> barrier -> 16 MFMA (one quadrant x K=64) -> barrier}.
// Best-measured configuration (round 7: QKV 46.6 us, total 140.8 us).
// ---------------------------------------------------------------------------
template<int OUT_BF16>
__global__ __launch_bounds__(512, 2) void gemm256(const u16* __restrict__ A,
                                                  const u16* __restrict__ B,
                                                  void* __restrict__ Cv,
                                                  int K, int lda, int ldb, int ldc) {
  // [dbuf][A=0/B=1][ksub][tile16][lane] : 2*2*2*16*64*16B = 128 KB
  __shared__ bf16x8 LD[2][2][2][16][64];
  const int tid = threadIdx.x, lane = tid & 63, wv = tid >> 6;
  const int wr = wv >> 2, wc = wv & 3;            // 2 x 4 wave grid

  // XCD-chunked bijective swizzle (nwg % 8 == 0 for both uses: 192, 256)
  const int gx = gridDim.x;
  const int nwg = gx * gridDim.y;
  const int lin = blockIdx.y * gx + blockIdx.x;
  const int chunk = nwg >> 3;
  const int orig = (lin & 7) * chunk + (lin >> 3);
  const int bx = orig % gx, by = orig / gx;
  const int row0 = by * 256, col0 = bx * 256;
  const int NT = K >> 6;

  const int fr = lane & 15;            // row within a 16-row tile
  const int kg = (lane >> 4) << 3;     // k-offset within a 32-wide ksub

  // stage one part (2 gload_lds): part 0: A tiles wv | 1: A wv+8 | 2: B wv | 3: B wv+8
  auto stage2 = [&](int kt, int db, int part) {
    const int ab = part >> 1;
    const int j = part & 1;
    const int tile = wv + (j << 3);            // wave-uniform
    const u16* base = ab ? B : A;
    const int ld = ab ? ldb : lda;
    const int rc0 = ab ? col0 : row0;
    const u16* g = base + (size_t)(rc0 + tile * 16 + fr) * ld + kt * 64 + kg;
    gload16(g,      &LD[db][ab][0][tile][0]);
    gload16(g + 32, &LD[db][ab][1][tile][0]);
  };

  bf16x8 aq[4][2], bq[4][2];
  auto readAquad = [&](int db, int h) {
#pragma unroll
    for (int i = 0; i < 4; ++i)
#pragma unroll
      for (int s = 0; s < 2; ++s)
        aq[i][s] = LD[db][0][s][wr * 8 + h * 4 + i][lane];
  };
  auto readB2 = [&](int db, int nh) {
#pragma unroll
    for (int j = 0; j < 2; ++j)
#pragma unroll
      for (int s = 0; s < 2; ++s)
        bq[nh * 2 + j][s] = LD[db][1][s][wc * 4 + nh * 2 + j][lane];
  };

  f32x4 acc[8][4] = {};
  auto cluster = [&](int h, int nh) {
#pragma unroll
    for (int i = 0; i < 4; ++i)
#pragma unroll
      for (int j = 0; j < 2; ++j)
#pragma unroll
        for (int s = 0; s < 2; ++s)
          acc[h * 4 + i][nh * 2 + j] = __builtin_amdgcn_mfma_f32_16x16x32_bf16(
              aq[i][s], bq[nh * 2 + j][s], acc[h * 4 + i][nh * 2 + j], 0, 0, 0);
  };

  // prologue: fully stage K-tile 0 into dbuf 0
  stage2(0, 0, 0); stage2(0, 0, 1); stage2(0, 0, 2); stage2(0, 0, 3);

  for (int kt = 0; kt < NT; ++kt) {
    const int db = kt & 1;
    const bool pf = (kt + 1 < NT);
    // ---- phase 0: quadrant (h=0, nh=0) ----
    if (pf) stage2(kt + 1, db ^ 1, 0);
    if (pf) asm volatile("s_waitcnt vmcnt(2)" ::: "memory");  // kt landed; 2 newest fly
    else    asm volatile("s_waitcnt vmcnt(0)" ::: "memory");
    __builtin_amdgcn_s_barrier();        // every wave's kt staging visible
    asm volatile("" ::: "memory");       // pin reads below the barrier
    readAquad(db, 0);
    readB2(db, 0);
    __builtin_amdgcn_s_setprio(1); cluster(0, 0); __builtin_amdgcn_s_setprio(0);
    __builtin_amdgcn_s_barrier();
    // ---- phase 1: quadrant (0,1) ----
    readB2(db, 1);
    if (pf) stage2(kt + 1, db ^ 1, 1);
    __builtin_amdgcn_s_barrier();
    __builtin_amdgcn_s_setprio(1); cluster(0, 1); __builtin_amdgcn_s_setprio(0);
    __builtin_amdgcn_s_barrier();
    // ---- phase 2: quadrant (1,0) ----
    readAquad(db, 1);
    if (pf) stage2(kt + 1, db ^ 1, 2);
    __builtin_amdgcn_s_barrier();
    __builtin_amdgcn_s_setprio(1); cluster(1, 0); __builtin_amdgcn_s_setprio(0);
    __builtin_amdgcn_s_barrier();
    // ---- phase 3: quadrant (1,1) ----
    if (pf) stage2(kt + 1, db ^ 1, 3);
    __builtin_amdgcn_s_barrier();
    __builtin_amdgcn_s_setprio(1); cluster(1, 1); __builtin_amdgcn_s_setprio(0);
    __builtin_amdgcn_s_barrier();
  }

  // C/D layout: col = lane&15, row = (lane>>4)*4 + reg
  const int r4 = (lane >> 4) << 2;
  const int cc = lane & 15;
#pragma unroll
  for (int mi = 0; mi < 8; ++mi)
#pragma unroll
    for (int nj = 0; nj < 4; ++nj)
#pragma unroll
      for (int r = 0; r < 4; ++r) {
        int lr = wr * 128 + mi * 16 + r4 + r;
        int lc = wc * 64 + nj * 16 + cc;
        float vv = acc[mi][nj][r];
        if (OUT_BF16) ((u16*)Cv)[(size_t)(row0 + lr) * ldc + col0 + lc] = f2b(vv);
        else          ((float*)Cv)[(size_t)(row0 + lr) * ldc + col0 + lc] = vv;
      }
}

// ---------------------------------------------------------------------------
// 128x128 MFMA GEMM (proven), depth-3 gload_lds pipeline, counted vmcnt.
// Used for the small batched modes only.
// ---------------------------------------------------------------------------
#define M_OUTER 2   // A=vT,B=kT (ld 16384), K=256 per chunk t, C=outer[t]*scale
#define M_RETR  3   // A=q (qkv ld 768, chunk rows), B=Mprev_b[t] bf16 (ld 256)

template<int MODE>
__global__ __launch_bounds__(256) void gemm128(const u16* __restrict__ A,
                                               const u16* __restrict__ Bg,
                                               void* __restrict__ Cv,
                                               int K, int lda, int ldb,
                                               float scale) {
  __shared__ bf16x8 As[3][512];
  __shared__ bf16x8 Bs[3][512];
  const int tid = threadIdx.x, lane = tid & 63, wv = tid >> 6;
  const int wr = wv >> 1, wc = wv & 1;
  const int t = blockIdx.z;
  const int bx = blockIdx.x, by = blockIdx.y;
  const int row0 = by * 128;
  const int col0 = bx * 128;
  const int NK = K >> 5;
  const u16* Bbase = (MODE == M_RETR) ? (Bg + (size_t)t * (MM * MM)) : Bg;

  auto stage = [&](int ks, int buf) {
    int koff;
    if (MODE == M_OUTER) koff = ((ks >> 1) << 12) + t * CHUNK + ((ks & 1) << 5);
    else                 koff = ks << 5;
#pragma unroll
    for (int j = 0; j < 2; ++j) {
      int m = j * 4 + wv;
      int rf = m * 16 + (lane & 15);
      size_t arow;
      if (MODE == M_RETR)
        arow = (size_t)(2 * by + (rf >> 6)) * SS + (size_t)t * CHUNK + (rf & 63);
      else
        arow = (size_t)(row0 + rf);
      const u16* ga = A + arow * (size_t)lda + koff + ((lane >> 4) << 3);
      gload16(ga, &As[buf][m * 64]);
      const u16* gb = Bbase + (size_t)(col0 + rf) * ldb + koff + ((lane >> 4) << 3);
      gload16(gb, &Bs[buf][m * 64]);
    }
  };

  f32x4 acc[4][4] = {};
  stage(0, 0);
  stage(1, 1);
  int rb = 0, sb = 2;
  for (int ks = 0; ks < NK; ++ks) {
    if (ks + 1 < NK) asm volatile("s_waitcnt vmcnt(4)" ::: "memory");
    else             asm volatile("s_waitcnt vmcnt(0)" ::: "memory");
    __builtin_amdgcn_s_barrier();
    asm volatile("" ::: "memory");
    if (ks + 2 < NK) stage(ks + 2, sb);
    bf16x8 af[4], bfr[4];
#pragma unroll
    for (int m = 0; m < 4; ++m) af[m] = As[rb][(wr * 4 + m) * 64 + lane];
#pragma unroll
    for (int n = 0; n < 4; ++n) bfr[n] = Bs[rb][(wc * 4 + n) * 64 + lane];
#pragma unroll
    for (int m = 0; m < 4; ++m)
#pragma unroll
      for (int n = 0; n < 4; ++n)
        acc[m][n] = __builtin_amdgcn_mfma_f32_16x16x32_bf16(af[m], bfr[n], acc[m][n], 0, 0, 0);
    rb = (rb == 2) ? 0 : rb + 1;
    sb = (sb == 2) ? 0 : sb + 1;
  }

  const int r4 = (lane >> 4) << 2;
  const int cc = lane & 15;
#pragma unroll
  for (int m = 0; m < 4; ++m)
#pragma unroll
    for (int n = 0; n < 4; ++n)
#pragma unroll
      for (int r = 0; r < 4; ++r) {
        int lr = wr * 64 + m * 16 + r4 + r;
        int lc = wc * 64 + n * 16 + cc;
        float vv = acc[m][n][r];
        if (MODE == M_OUTER) {
          ((float*)Cv)[(size_t)t * (MM * MM) + (size_t)(row0 + lr) * MM + col0 + lc] = vv * scale;
        } else {  // M_RETR
          size_t rowg = (size_t)(2 * by + (lr >> 6)) * SS + (size_t)t * CHUNK + (lr & 63);
          ((u16*)Cv)[rowg * MM + col0 + lc] = f2b(vv);
        }
      }
}

// ---------------------------------------------------------------------------
// Fused l2norm + transpose: qkv cols [256,512)=k, [512,768)=v -> kT,vT
// ---------------------------------------------------------------------------
__global__ __launch_bounds__(256) void l2normT_kernel(const u16* __restrict__ qkv,
                                                      u16* __restrict__ kT,
                                                      u16* __restrict__ vT) {
  __shared__ u16 T[256][72];
  __shared__ float ps[64][4];
  __shared__ float inv[64];
  const int tid = threadIdx.x;
  const int q = tid >> 6, rl = tid & 63;
  const int row0 = blockIdx.x * 64;
#pragma unroll 1
  for (int seg = 0; seg < 2; ++seg) {
    u16* dstT = seg ? vT : kT;
    const int segbase = 256 + seg * 256;
    float ss = 0.f;
#pragma unroll
    for (int i = 0; i < 8; ++i) {
      u16x8 v = *reinterpret_cast<const u16x8*>(
          qkv + (size_t)(row0 + rl) * QKV_LD + segbase + q * 64 + i * 8);
#pragma unroll
      for (int e = 0; e < 8; ++e) {
        float f = b2f(v[e]);
        ss += f * f;
        T[q * 64 + i * 8 + e][rl] = v[e];
      }
    }
    ps[rl][q] = ss;
    __syncthreads();
    if (tid < 64) {
      float s = ps[tid][0] + ps[tid][1] + ps[tid][2] + ps[tid][3];
      inv[tid] = 1.0f / fmaxf(sqrtf(s), 1e-12f);
    }
    __syncthreads();
#pragma unroll
    for (int p = 0; p < 8; ++p) {
      int c = p * 32 + q * 8 + (rl >> 3);
      int r0 = (rl & 7) * 8;
      u16x8 val = *reinterpret_cast<const u16x8*>(&T[c][r0]);
      u16x8 o;
#pragma unroll
      for (int e = 0; e < 8; ++e) o[e] = f2b(b2f(val[e]) * inv[r0 + e]);
      *reinterpret_cast<u16x8*>(dstT + (size_t)c * ROWS + row0 + r0) = o;
    }
    __syncthreads();
  }
}

// ---------------------------------------------------------------------------
// Decay prefix over t: Mprev_b[t] = bf16(run); run = decay*run + outer[t].
// ---------------------------------------------------------------------------
__global__ __launch_bounds__(256) void prefix_kernel(const float* __restrict__ outer,
                                                     const float* __restrict__ M0,
                                                     u16* __restrict__ Mprev_b,
                                                     float decay_c) {
  int ij = blockIdx.x * 256 + threadIdx.x;
  float run = M0[ij];
  float pre[8];
#pragma unroll
  for (int d = 0; d < 8; ++d) pre[d] = outer[(size_t)d * (MM * MM) + ij];
#pragma unroll 1
  for (int tb = 0; tb < NCHUNK; tb += 8) {
#pragma unroll
    for (int d = 0; d < 8; ++d) {
      int tc = tb + d;
      float o = pre[d];
      if (tb + 8 < NCHUNK) pre[d] = outer[(size_t)(tc + 8) * (MM * MM) + ij];
      Mprev_b[(size_t)tc * (MM * MM) + ij] = f2b(run);
      run = decay_c * run + o;
    }
  }
}

// ---------------------------------------------------------------------------
extern "C" void kernel_launch(void* const* d_in, const int* in_sizes, int n_in,
                              void* d_out, int out_size, void* d_ws, size_t ws_size,
                              hipStream_t stream) {
  const float* x  = (const float*)d_in[0];
  const float* Wq = (const float*)d_in[1];
  const float* Wk = (const float*)d_in[2];
  const float* Wv = (const float*)d_in[3];
  const float* Wo = (const float*)d_in[4];
  const float* M0 = (const float*)d_in[5];
  float* out = (float*)d_out;

  char* ws = (char*)d_ws;
  u16*   xb      = (u16*)(ws);               // 16384x1024 bf16 (32M)
  u16*   qkv_b   = (u16*)(ws + 33554432);    // 16384x768 bf16 (24M)
  u16*   Wqkv_b  = (u16*)(ws + 58720256);    // 768x1024 bf16 (1.5M)
  u16*   Wo_b    = (u16*)(ws + 60293120);    // 1024x256 bf16 (0.5M)
  u16*   kT      = (u16*)(ws);               // 8M, over dead xb
  u16*   vT      = (u16*)(ws + 8388608);     // 8M
  float* outer   = (float*)(ws + 16777216);  // 64x256x256 fp32 (16M)
  u16*   Mprev_b = (u16*)(ws);               // 8M, over dead kT
  u16*   r_b     = (u16*)(ws + 8388608);     // 8M, over dead vT

  const float scale   = 1.0f / (BB * CHUNK);
  const float decay_c = (float)pow(DECAY_F, (double)CHUNK);
  dim3 blk(256), blk512(512);

  // 1) casts
  cast_x_kernel<<<(ROWS * HH / 4) / 256, blk, 0, stream>>>(x, xb);
  cast_w_kernel<<<1024, blk, 0, stream>>>(Wq, Wk, Wv, Wo, Wqkv_b, Wo_b);
  // 2) fused QKV projection: (16384x1024)x(768x1024)^T -> qkv_b (8-phase 256^2)
  gemm256<1><<<dim3(QKV_LD / 256, ROWS / 256), blk512, 0, stream>>>(
      xb, Wqkv_b, qkv_b, HH, HH, HH, QKV_LD);
  // 3) l2norm k,v + transpose -> kT, vT
  l2normT_kernel<<<ROWS / 64, blk, 0, stream>>>(qkv_b, kT, vT);
  // 4) per-chunk outer products: outer[t] = scale * vT_t * kT_t^T
  gemm128<M_OUTER><<<dim3(2, 2, NCHUNK), blk, 0, stream>>>(
      vT, kT, outer, MM, ROWS, ROWS, scale);
  // 5) decay prefix scan -> Mprev_b (bf16)
  prefix_kernel<<<(MM * MM) / 256, blk, 0, stream>>>(outer, M0, Mprev_b, decay_c);
  // 6) retrieval: r = q @ Mprev_b[t]^T -> r_b (bf16)
  gemm128<M_RETR><<<dim3(2, 2, NCHUNK), blk, 0, stream>>>(
      qkv_b, Mprev_b, r_b, MM, QKV_LD, MM, 0.f);
  // 7) output projection: (16384x256)x(1024x256)^T -> fp32 out (8-phase 256^2)
  gemm256<0><<<dim3(HH / 256, ROWS / 256), blk512, 0, stream>>>(
      r_b, Wo_b, out, MM, MM, MM, HH);
}

// Round 14
// 134.254 us; speedup vs baseline: 1.1241x; 1.0446x over previous
//
#include <hip/hip_runtime.h>
#include <math.h>

// Problem constants: B=4, S=4096, H=1024, M=256, chunk=64
#define BB 4
#define SS 4096
#define HH 1024
#define MM 256
#define CHUNK 64
#define NCHUNK 64
#define ROWS (BB*SS)          // 16384
#define DECAY_F 0.99

typedef unsigned short u16;
typedef __attribute__((ext_vector_type(8))) short bf16x8;
typedef __attribute__((ext_vector_type(8))) unsigned short u16x8;
typedef __attribute__((ext_vector_type(4))) float f32x4;

__device__ inline u16 f2b(float f) {
  union { float f; unsigned u; } v; v.f = f;
  unsigned r = v.u + 0x7FFF + ((v.u >> 16) & 1);   // RNE
  return (u16)(r >> 16);
}
__device__ inline float b2f(u16 h) {
  union { unsigned u; float f; } v; v.u = ((unsigned)h) << 16; return v.f;
}

// async global->LDS, 16B per lane. LDS dest wave-uniform base; global src per-lane.
__device__ inline void gload16(const void* g, void* l) {
  __builtin_amdgcn_global_load_lds(
      (const __attribute__((address_space(1))) unsigned int*)g,
      (__attribute__((address_space(3))) unsigned int*)l, 16, 0, 0);
}

// ---------------------------------------------------------------------------
// All input casts in one launch: x (16384 blocks) + 4 weights (1024 blocks).
// ---------------------------------------------------------------------------
__global__ __launch_bounds__(256) void cast_all_kernel(const float* __restrict__ x,
                                                       const float* __restrict__ Wq,
                                                       const float* __restrict__ Wk,
                                                       const float* __restrict__ Wv,
                                                       const float* __restrict__ Wo,
                                                       u16* __restrict__ xb,
                                                       u16* __restrict__ Wqkv_b,
                                                       u16* __restrict__ Wo_b) {
  int b = blockIdx.x;
  const float* src;
  u16* dst;
  int i;
  if (b < 16384) {                       // x: 16384*1024 = 16.77M elems / 4
    src = x; dst = xb; i = (b << 8) + threadIdx.x;
  } else {
    int wb = b - 16384, which = wb >> 8;
    i = ((wb & 255) << 8) + threadIdx.x;
    src = which == 0 ? Wq : which == 1 ? Wk : which == 2 ? Wv : Wo;
    dst = which < 3 ? Wqkv_b + which * (MM * HH) : Wo_b;
  }
  float4 v = reinterpret_cast<const float4*>(src)[i];
  ushort4 o;
  o.x = f2b(v.x); o.y = f2b(v.y); o.z = f2b(v.z); o.w = f2b(v.w);
  reinterpret_cast<ushort4*>(dst)[i] = o;
}

// ---------------------------------------------------------------------------
// 256x256 8-phase MFMA GEMM (C = A * B^T), 512 thr = 8 waves (2M x 4N),
// wave tile 128x64, BK=64, fragment-major conflict-free LDS, gload_lds
// staging, counted vmcnt(2), setprio MFMA clusters. K-loop = round-7 proven
// schedule, UNTOUCHED.
// EPI=0: C fp32 row-major ldc (output projection).
// EPI=2: QKV fused epilogue -- bx==0: q -> q_b (bf16, ld 256);
//        bx==1/2: k/v l2norm (fp32 acc) + TRANSPOSED bf16 write to kT/vT.
//        Replaces the separate l2normT kernel.
// ---------------------------------------------------------------------------
template<int EPI>
__global__ __launch_bounds__(512, 2) void gemm256(const u16* __restrict__ A,
                                                  const u16* __restrict__ B,
                                                  void* __restrict__ Cv,
                                                  u16* __restrict__ kTd,
                                                  u16* __restrict__ vTd,
                                                  int K, int lda, int ldb, int ldc) {
  // [dbuf][A=0/B=1][ksub][tile16][lane] : 2*2*2*16*64*16B = 128 KB
  __shared__ bf16x8 LD[2][2][2][16][64];
  const int tid = threadIdx.x, lane = tid & 63, wv = tid >> 6;
  const int wr = wv >> 2, wc = wv & 3;            // 2 x 4 wave grid

  // XCD-chunked bijective swizzle (nwg % 8 == 0 for both uses: 192, 256)
  const int gx = gridDim.x;
  const int nwg = gx * gridDim.y;
  const int lin = blockIdx.y * gx + blockIdx.x;
  const int chunk = nwg >> 3;
  const int orig = (lin & 7) * chunk + (lin >> 3);
  const int bx = orig % gx, by = orig / gx;
  const int row0 = by * 256, col0 = bx * 256;
  const int NT = K >> 6;

  const int fr = lane & 15;            // row within a 16-row tile
  const int kg = (lane >> 4) << 3;     // k-offset within a 32-wide ksub

  auto stage2 = [&](int kt, int db, int part) {
    const int ab = part >> 1;
    const int j = part & 1;
    const int tile = wv + (j << 3);            // wave-uniform
    const u16* base = ab ? B : A;
    const int ld = ab ? ldb : lda;
    const int rc0 = ab ? col0 : row0;
    const u16* g = base + (size_t)(rc0 + tile * 16 + fr) * ld + kt * 64 + kg;
    gload16(g,      &LD[db][ab][0][tile][0]);
    gload16(g + 32, &LD[db][ab][1][tile][0]);
  };

  bf16x8 aq[4][2], bq[4][2];
  auto readAquad = [&](int db, int h) {
#pragma unroll
    for (int i = 0; i < 4; ++i)
#pragma unroll
      for (int s = 0; s < 2; ++s)
        aq[i][s] = LD[db][0][s][wr * 8 + h * 4 + i][lane];
  };
  auto readB2 = [&](int db, int nh) {
#pragma unroll
    for (int j = 0; j < 2; ++j)
#pragma unroll
      for (int s = 0; s < 2; ++s)
        bq[nh * 2 + j][s] = LD[db][1][s][wc * 4 + nh * 2 + j][lane];
  };

  f32x4 acc[8][4] = {};
  auto cluster = [&](int h, int nh) {
#pragma unroll
    for (int i = 0; i < 4; ++i)
#pragma unroll
      for (int j = 0; j < 2; ++j)
#pragma unroll
        for (int s = 0; s < 2; ++s)
          acc[h * 4 + i][nh * 2 + j] = __builtin_amdgcn_mfma_f32_16x16x32_bf16(
              aq[i][s], bq[nh * 2 + j][s], acc[h * 4 + i][nh * 2 + j], 0, 0, 0);
  };

  // prologue: fully stage K-tile 0 into dbuf 0
  stage2(0, 0, 0); stage2(0, 0, 1); stage2(0, 0, 2); stage2(0, 0, 3);

  for (int kt = 0; kt < NT; ++kt) {
    const int db = kt & 1;
    const bool pf = (kt + 1 < NT);
    // ---- phase 0 ----
    if (pf) stage2(kt + 1, db ^ 1, 0);
    if (pf) asm volatile("s_waitcnt vmcnt(2)" ::: "memory");
    else    asm volatile("s_waitcnt vmcnt(0)" ::: "memory");
    __builtin_amdgcn_s_barrier();
    asm volatile("" ::: "memory");
    readAquad(db, 0);
    readB2(db, 0);
    __builtin_amdgcn_s_setprio(1); cluster(0, 0); __builtin_amdgcn_s_setprio(0);
    __builtin_amdgcn_s_barrier();
    // ---- phase 1 ----
    readB2(db, 1);
    if (pf) stage2(kt + 1, db ^ 1, 1);
    __builtin_amdgcn_s_barrier();
    __builtin_amdgcn_s_setprio(1); cluster(0, 1); __builtin_amdgcn_s_setprio(0);
    __builtin_amdgcn_s_barrier();
    // ---- phase 2 ----
    readAquad(db, 1);
    if (pf) stage2(kt + 1, db ^ 1, 2);
    __builtin_amdgcn_s_barrier();
    __builtin_amdgcn_s_setprio(1); cluster(1, 0); __builtin_amdgcn_s_setprio(0);
    __builtin_amdgcn_s_barrier();
    // ---- phase 3 ----
    if (pf) stage2(kt + 1, db ^ 1, 3);
    __builtin_amdgcn_s_barrier();
    __builtin_amdgcn_s_setprio(1); cluster(1, 1); __builtin_amdgcn_s_setprio(0);
    __builtin_amdgcn_s_barrier();
  }

  // C/D layout: col = lane&15, row = (lane>>4)*4 + reg
  const int r4 = (lane >> 4) << 2;
  const int cc = lane & 15;

  if constexpr (EPI == 0) {
#pragma unroll
    for (int mi = 0; mi < 8; ++mi)
#pragma unroll
      for (int nj = 0; nj < 4; ++nj)
#pragma unroll
        for (int r = 0; r < 4; ++r) {
          int lr = wr * 128 + mi * 16 + r4 + r;
          int lc = wc * 64 + nj * 16 + cc;
          ((float*)Cv)[(size_t)(row0 + lr) * ldc + col0 + lc] = acc[mi][nj][r];
        }
  } else {
    if (bx == 0) {
      // q: plain bf16 write, ld MM into q_b
#pragma unroll
      for (int mi = 0; mi < 8; ++mi)
#pragma unroll
        for (int nj = 0; nj < 4; ++nj)
#pragma unroll
          for (int r = 0; r < 4; ++r) {
            int lr = wr * 128 + mi * 16 + r4 + r;
            int lc = wc * 64 + nj * 16 + cc;
            ((u16*)Cv)[(size_t)(row0 + lr) * MM + lc] = f2b(acc[mi][nj][r]);
          }
    } else {
      // k/v: fp32 l2norm over the full 256-col row + transposed bf16 write
      u16* dstT = (bx == 1) ? kTd : vTd;
      __syncthreads();                                   // LD dead -> reuse
      float* ps = reinterpret_cast<float*>(&LD[0][0][0][0][0]);  // [256][4]
#pragma unroll
      for (int mi = 0; mi < 8; ++mi)
#pragma unroll
        for (int r = 0; r < 4; ++r) {
          float p = 0.f;
#pragma unroll
          for (int nj = 0; nj < 4; ++nj) {
            float v = acc[mi][nj][r];
            p += v * v;
          }
          // reduce over the 16 cc lanes (lane-group preserved by masks<16)
          p += __shfl_xor(p, 1);
          p += __shfl_xor(p, 2);
          p += __shfl_xor(p, 4);
          p += __shfl_xor(p, 8);
          if (cc == 0)
            ps[(wr * 128 + mi * 16 + (lane >> 4) * 4 + r) * 4 + wc] = p;
        }
      __syncthreads();
#pragma unroll
      for (int mi = 0; mi < 8; ++mi) {
        int rowb = wr * 128 + mi * 16 + r4;              // 4 consecutive rows
        float4 s0 = *reinterpret_cast<float4*>(&ps[(rowb + 0) * 4]);
        float4 s1 = *reinterpret_cast<float4*>(&ps[(rowb + 1) * 4]);
        float4 s2 = *reinterpret_cast<float4*>(&ps[(rowb + 2) * 4]);
        float4 s3 = *reinterpret_cast<float4*>(&ps[(rowb + 3) * 4]);
        float iv0 = 1.0f / fmaxf(sqrtf(s0.x + s0.y + s0.z + s0.w), 1e-12f);
        float iv1 = 1.0f / fmaxf(sqrtf(s1.x + s1.y + s1.z + s1.w), 1e-12f);
        float iv2 = 1.0f / fmaxf(sqrtf(s2.x + s2.y + s2.z + s2.w), 1e-12f);
        float iv3 = 1.0f / fmaxf(sqrtf(s3.x + s3.y + s3.z + s3.w), 1e-12f);
#pragma unroll
        for (int nj = 0; nj < 4; ++nj) {
          int col = wc * 64 + nj * 16 + cc;              // 0..255 within segment
          ushort4 o;
          o.x = f2b(acc[mi][nj][0] * iv0);
          o.y = f2b(acc[mi][nj][1] * iv1);
          o.z = f2b(acc[mi][nj][2] * iv2);
          o.w = f2b(acc[mi][nj][3] * iv3);
          *reinterpret_cast<ushort4*>(&dstT[(size_t)col * ROWS + row0 + rowb]) = o;
        }
      }
    }
  }
}

// ---------------------------------------------------------------------------
// 128x128 MFMA GEMM (proven), depth-3 gload_lds pipeline, counted vmcnt.
// ---------------------------------------------------------------------------
#define M_OUTER 2   // A=vT,B=kT (ld 16384), K=256 per chunk t, C=outer[t]*scale
#define M_RETR  3   // A=q_b (ld 256, chunk rows), B=Mprev_b[t] bf16 (ld 256)

template<int MODE>
__global__ __launch_bounds__(256) void gemm128(const u16* __restrict__ A,
                                               const u16* __restrict__ Bg,
                                               void* __restrict__ Cv,
                                               int K, int lda, int ldb,
                                               float scale) {
  __shared__ bf16x8 As[3][512];
  __shared__ bf16x8 Bs[3][512];
  const int tid = threadIdx.x, lane = tid & 63, wv = tid >> 6;
  const int wr = wv >> 1, wc = wv & 1;
  const int t = blockIdx.z;
  const int bx = blockIdx.x, by = blockIdx.y;
  const int row0 = by * 128;
  const int col0 = bx * 128;
  const int NK = K >> 5;
  const u16* Bbase = (MODE == M_RETR) ? (Bg + (size_t)t * (MM * MM)) : Bg;

  auto stage = [&](int ks, int buf) {
    int koff;
    if (MODE == M_OUTER) koff = ((ks >> 1) << 12) + t * CHUNK + ((ks & 1) << 5);
    else                 koff = ks << 5;
#pragma unroll
    for (int j = 0; j < 2; ++j) {
      int m = j * 4 + wv;
      int rf = m * 16 + (lane & 15);
      size_t arow;
      if (MODE == M_RETR)
        arow = (size_t)(2 * by + (rf >> 6)) * SS + (size_t)t * CHUNK + (rf & 63);
      else
        arow = (size_t)(row0 + rf);
      const u16* ga = A + arow * (size_t)lda + koff + ((lane >> 4) << 3);
      gload16(ga, &As[buf][m * 64]);
      const u16* gb = Bbase + (size_t)(col0 + rf) * ldb + koff + ((lane >> 4) << 3);
      gload16(gb, &Bs[buf][m * 64]);
    }
  };

  f32x4 acc[4][4] = {};
  stage(0, 0);
  stage(1, 1);
  int rb = 0, sb = 2;
  for (int ks = 0; ks < NK; ++ks) {
    if (ks + 1 < NK) asm volatile("s_waitcnt vmcnt(4)" ::: "memory");
    else             asm volatile("s_waitcnt vmcnt(0)" ::: "memory");
    __builtin_amdgcn_s_barrier();
    asm volatile("" ::: "memory");
    if (ks + 2 < NK) stage(ks + 2, sb);
    bf16x8 af[4], bfr[4];
#pragma unroll
    for (int m = 0; m < 4; ++m) af[m] = As[rb][(wr * 4 + m) * 64 + lane];
#pragma unroll
    for (int n = 0; n < 4; ++n) bfr[n] = Bs[rb][(wc * 4 + n) * 64 + lane];
#pragma unroll
    for (int m = 0; m < 4; ++m)
#pragma unroll
      for (int n = 0; n < 4; ++n)
        acc[m][n] = __builtin_amdgcn_mfma_f32_16x16x32_bf16(af[m], bfr[n], acc[m][n], 0, 0, 0);
    rb = (rb == 2) ? 0 : rb + 1;
    sb = (sb == 2) ? 0 : sb + 1;
  }

  const int r4 = (lane >> 4) << 2;
  const int cc = lane & 15;
#pragma unroll
  for (int m = 0; m < 4; ++m)
#pragma unroll
    for (int n = 0; n < 4; ++n)
#pragma unroll
      for (int r = 0; r < 4; ++r) {
        int lr = wr * 64 + m * 16 + r4 + r;
        int lc = wc * 64 + n * 16 + cc;
        float vv = acc[m][n][r];
        if (MODE == M_OUTER) {
          ((float*)Cv)[(size_t)t * (MM * MM) + (size_t)(row0 + lr) * MM + col0 + lc] = vv * scale;
        } else {  // M_RETR
          size_t rowg = (size_t)(2 * by + (lr >> 6)) * SS + (size_t)t * CHUNK + (lr & 63);
          ((u16*)Cv)[rowg * MM + col0 + lc] = f2b(vv);
        }
      }
}

// ---------------------------------------------------------------------------
// Decay prefix over t: Mprev_b[t] = bf16(run); run = decay*run + outer[t].
// ---------------------------------------------------------------------------
__global__ __launch_bounds__(256) void prefix_kernel(const float* __restrict__ outer,
                                                     const float* __restrict__ M0,
                                                     u16* __restrict__ Mprev_b,
                                                     float decay_c) {
  int ij = blockIdx.x * 256 + threadIdx.x;
  float run = M0[ij];
  float pre[8];
#pragma unroll
  for (int d = 0; d < 8; ++d) pre[d] = outer[(size_t)d * (MM * MM) + ij];
#pragma unroll 1
  for (int tb = 0; tb < NCHUNK; tb += 8) {
#pragma unroll
    for (int d = 0; d < 8; ++d) {
      int tc = tb + d;
      float o = pre[d];
      if (tb + 8 < NCHUNK) pre[d] = outer[(size_t)(tc + 8) * (MM * MM) + ij];
      Mprev_b[(size_t)tc * (MM * MM) + ij] = f2b(run);
      run = decay_c * run + o;
    }
  }
}

// ---------------------------------------------------------------------------
extern "C" void kernel_launch(void* const* d_in, const int* in_sizes, int n_in,
                              void* d_out, int out_size, void* d_ws, size_t ws_size,
                              hipStream_t stream) {
  const float* x  = (const float*)d_in[0];
  const float* Wq = (const float*)d_in[1];
  const float* Wk = (const float*)d_in[2];
  const float* Wv = (const float*)d_in[3];
  const float* Wo = (const float*)d_in[4];
  const float* M0 = (const float*)d_in[5];
  float* out = (float*)d_out;

  char* ws = (char*)d_ws;
  u16*   xb      = (u16*)(ws);               // [0,32M)  bf16 x; dead after QKV
  u16*   q_b     = (u16*)(ws + 33554432);    // [32,40M) 16384x256 bf16
  u16*   kT      = (u16*)(ws + 41943040);    // [40,48M) 256x16384 bf16
  u16*   vT      = (u16*)(ws + 50331648);    // [48,56M) 256x16384 bf16
  u16*   Wqkv_b  = (u16*)(ws + 58720256);    // [56,57.5M)
  u16*   Wo_b    = (u16*)(ws + 60293120);    // [57.5,58M)
  float* outer   = (float*)(ws);             // [0,16M)  over dead xb
  u16*   Mprev_b = (u16*)(ws + 16777216);    // [16,24M) over dead xb
  u16*   r_b     = (u16*)(ws + 41943040);    // [40,48M) over dead kT

  const float scale   = 1.0f / (BB * CHUNK);
  const float decay_c = (float)pow(DECAY_F, (double)CHUNK);
  dim3 blk(256), blk512(512);

  // 1) all casts in one launch (x + 4 weights)
  cast_all_kernel<<<16384 + 1024, blk, 0, stream>>>(x, Wq, Wk, Wv, Wo,
                                                    xb, Wqkv_b, Wo_b);
  // 2) fused QKV projection + l2norm + transpose epilogue:
  //    q -> q_b; k,v -> normalized kT,vT (l2normT kernel eliminated)
  gemm256<2><<<dim3(3, ROWS / 256), blk512, 0, stream>>>(
      xb, Wqkv_b, q_b, kT, vT, HH, HH, HH, MM);
  // 3) per-chunk outer products: outer[t] = scale * vT_t * kT_t^T
  gemm128<M_OUTER><<<dim3(2, 2, NCHUNK), blk, 0, stream>>>(
      vT, kT, outer, MM, ROWS, ROWS, scale);
  // 4) decay prefix scan -> Mprev_b (bf16)
  prefix_kernel<<<(MM * MM) / 256, blk, 0, stream>>>(outer, M0, Mprev_b, decay_c);
  // 5) retrieval: r = q @ Mprev_b[t]^T -> r_b (bf16)
  gemm128<M_RETR><<<dim3(2, 2, NCHUNK), blk, 0, stream>>>(
      q_b, Mprev_b, r_b, MM, MM, MM, 0.f);
  // 6) output projection: (16384x256)x(1024x256)^T -> fp32 out
  gemm256<0><<<dim3(HH / 256, ROWS / 256), blk512, 0, stream>>>(
      r_b, Wo_b, out, nullptr, nullptr, MM, MM, MM, HH);
}